// Round 5
// baseline (310.111 us; speedup 1.0000x reference)
//
#include <hip/hip_runtime.h>
#include <math.h>

#define B_      4
#define IN_DIM  512
#define HID     1024
#define SEQ     4096
#define MID_DIM 12352          // 2*64*64 + 65*64
#define MLP_OUT 24897          // RL*MID_DIM + OUT_DIM
#define INV2PI  0.15915494309189535f

// transposed/pre-scaled weight layout, per b (stride MLPT_STRIDE):
//  layer l in {0,1} at l*12416: wsc[i][o] | wof[i][o] | bsv[i][o] | bc[o] | pad64
//  out layer at 24832: wsO/2pi (64) | woO/2pi (64) | bsO (64) | bcO | pad to 256
#define MLPT_STRIDE 25088

// ---- workspace layout (float offsets) ----
#define OFF_P0    0            // 8*4*1024 = 32768
#define OFF_P1    32768        // 4*4*1024 = 16384
#define OFF_P2    49152        // 4*4*1024 = 16384
#define OFF_MLPT  65536        // 4*25088  = 100352

__device__ __forceinline__ float gelu_exact(float v) {
    return 0.5f * v * (1.0f + erff(v * 0.70710678118654752f));
}

__device__ __forceinline__ float hw_sin_rev(float r) {
    r = r - __builtin_rintf(r);
    return __builtin_amdgcn_sinf(r);
}

// ---------- x(4x512) @ w0 -> p0 (8 K-partials): grid (16,8), block 256 ----------
__global__ void k_gemm0(const float* __restrict__ x, const float* __restrict__ w0,
                        float* __restrict__ p0) {
    const int cch = blockIdx.x, kc = blockIdx.y;
    const int tid = threadIdx.x;
    __shared__ float xs[256];                 // [b][k64]
    {
        const int b = tid >> 6, k = tid & 63;
        xs[tid] = x[b * IN_DIM + kc * 64 + k];
    }
    __syncthreads();
    const int b = tid >> 6, cl = tid & 63;
    const int c = cch * 64 + cl;
    const float* wp = w0 + (size_t)(kc * 64) * HID + c;
    const float* xp = xs + b * 64;
    float acc = 0.f;
    #pragma unroll 16
    for (int k = 0; k < 64; ++k) acc = fmaf(xp[k], wp[(size_t)k * HID], acc);
    p0[(kc * 4 + b) * HID + c] = acc;
}

// ---------- h0=gelu(sum8 p0 + b0); h0 @ w1 -> p1 (4 K-partials): grid (16,4) ----------
__global__ void k_gemm1(const float* __restrict__ p0, const float* __restrict__ b0,
                        const float* __restrict__ w1, float* __restrict__ p1) {
    const int cch = blockIdx.x, kc = blockIdx.y;   // kc: 256-wide k slice
    const int tid = threadIdx.x;
    __shared__ float s_h[1024];               // [b][k256]
    for (int e = tid; e < 1024; e += 256) {
        const int b = e >> 8, kk = e & 255;
        const int kg = kc * 256 + kk;
        float v = b0[kg];
        #pragma unroll
        for (int j = 0; j < 8; ++j) v += p0[(j * 4 + b) * HID + kg];
        s_h[e] = gelu_exact(v);
    }
    __syncthreads();
    const int b = tid >> 6, cl = tid & 63;
    const int c = cch * 64 + cl;
    const float* wp = w1 + (size_t)(kc * 256) * HID + c;
    const float* hp = s_h + b * 256;
    float acc = 0.f;
    #pragma unroll 16
    for (int k = 0; k < 256; ++k) acc = fmaf(hp[k], wp[(size_t)k * HID], acc);
    p1[(kc * 4 + b) * HID + c] = acc;
}

// ---------- h1=gelu(LN(sum4 p1 + b1)) per block; h1 @ w2 -> p2 (4 K-partials): grid (16,4) ----------
__global__ void k_gemm2(const float* __restrict__ p1, const float* __restrict__ b1,
                        const float* __restrict__ g1, const float* __restrict__ bl1,
                        const float* __restrict__ w2, float* __restrict__ p2) {
    const int cch = blockIdx.x, kc = blockIdx.y;
    const int tid = threadIdx.x;
    __shared__ __align__(16) float vbuf[4096];   // [b][c]
    __shared__ float s_h[1024];                  // [b][k256]
    __shared__ float s_red[8];
    for (int e = tid; e < 4096; e += 256) {
        const int b = e >> 10, c = e & 1023;
        float v = b1[c];
        #pragma unroll
        for (int j = 0; j < 4; ++j) v += p1[(j * 4 + b) * HID + c];
        vbuf[e] = v;
    }
    __syncthreads();
    {
        const int b = tid >> 6, lane = tid & 63;
        float s1 = 0.f, s2 = 0.f;
        #pragma unroll
        for (int jj = 0; jj < 16; ++jj) {
            const float v = vbuf[b * 1024 + lane + 64 * jj];
            s1 += v; s2 += v * v;
        }
        #pragma unroll
        for (int m = 1; m < 64; m <<= 1) {
            s1 += __shfl_xor(s1, m, 64);
            s2 += __shfl_xor(s2, m, 64);
        }
        if (lane == 0) {
            const float mu = s1 * (1.0f / HID);
            s_red[b] = mu;
            s_red[4 + b] = rsqrtf(s2 * (1.0f / HID) - mu * mu + 1e-5f);
        }
    }
    __syncthreads();
    for (int e = tid; e < 1024; e += 256) {
        const int b = e >> 8, kk = e & 255;
        const int c = kc * 256 + kk;
        const float v = vbuf[b * 1024 + c];
        s_h[e] = gelu_exact((v - s_red[b]) * s_red[4 + b] * g1[c] + bl1[c]);
    }
    __syncthreads();
    const int b = tid >> 6, cl = tid & 63;
    const int c = cch * 64 + cl;
    const float* wp = w2 + (size_t)(kc * 256) * HID + c;
    const float* hp = s_h + b * 256;
    float acc = 0.f;
    #pragma unroll 16
    for (int k = 0; k < 256; ++k) acc = fmaf(hp[k], wp[(size_t)k * HID], acc);
    p2[(kc * 4 + b) * HID + c] = acc;
}

// ---------- h2=gelu(LN(sum4 p2 + b2)) inline; h2 @ w3 -> atomicAdd into permuted mlpT ----------
// grid (98, 8): 98 col-chunks x 8 K-chunks of 128. block 256. thread = 1 col, 4 b-accs.
__global__ void k_gemm3T(const float* __restrict__ p2, const float* __restrict__ b2,
                         const float* __restrict__ g2, const float* __restrict__ bl2,
                         const float* __restrict__ w3, const float* __restrict__ b3,
                         float* __restrict__ mlpT) {
    const int colb = blockIdx.x;     // 0..97
    const int kc   = blockIdx.y;     // 0..7
    const int tid  = threadIdx.x;
    __shared__ __align__(16) float vbuf[4096];   // [b][c]
    __shared__ __align__(16) float s_h[512];     // [b][k128]
    __shared__ float s_red[8];

    for (int e = tid; e < 4096; e += 256) {
        const int b = e >> 10, c = e & 1023;
        float v = b2[c];
        #pragma unroll
        for (int j = 0; j < 4; ++j) v += p2[(j * 4 + b) * HID + c];
        vbuf[e] = v;
    }
    __syncthreads();
    {
        const int b = tid >> 6, lane = tid & 63;
        float s1 = 0.f, s2 = 0.f;
        #pragma unroll
        for (int jj = 0; jj < 16; ++jj) {
            const float v = vbuf[b * 1024 + lane + 64 * jj];
            s1 += v; s2 += v * v;
        }
        #pragma unroll
        for (int m = 1; m < 64; m <<= 1) {
            s1 += __shfl_xor(s1, m, 64);
            s2 += __shfl_xor(s2, m, 64);
        }
        if (lane == 0) {
            const float mu = s1 * (1.0f / HID);
            s_red[b] = mu;
            s_red[4 + b] = rsqrtf(s2 * (1.0f / HID) - mu * mu + 1e-5f);
        }
    }
    __syncthreads();
    for (int e = tid; e < 512; e += 256) {       // gelu(LN) for this block's 128-k chunk
        const int b = e >> 7, kk = e & 127;
        const int c = kc * 128 + kk;
        const float v = vbuf[b * 1024 + c];
        s_h[e] = gelu_exact((v - s_red[b]) * s_red[4 + b] * g2[c] + bl2[c]);
    }
    __syncthreads();

    const int c_raw = colb * 256 + tid;
    const bool valid = c_raw < MLP_OUT;
    const int c = valid ? c_raw : (MLP_OUT - 1);
    const float* wp = w3 + (size_t)(kc * 128) * MLP_OUT + c;
    float a0 = 0.f, a1 = 0.f, a2 = 0.f, a3 = 0.f;
    #pragma unroll 8
    for (int kk = 0; kk < 128; kk += 4) {
        const float wv0 = wp[(size_t)(kk + 0) * MLP_OUT];
        const float wv1 = wp[(size_t)(kk + 1) * MLP_OUT];
        const float wv2 = wp[(size_t)(kk + 2) * MLP_OUT];
        const float wv3 = wp[(size_t)(kk + 3) * MLP_OUT];
        const float4 h0 = *reinterpret_cast<const float4*>(&s_h[kk]);
        const float4 h1 = *reinterpret_cast<const float4*>(&s_h[128 + kk]);
        const float4 h2 = *reinterpret_cast<const float4*>(&s_h[256 + kk]);
        const float4 h3 = *reinterpret_cast<const float4*>(&s_h[384 + kk]);
        a0 = fmaf(h0.x, wv0, fmaf(h0.y, wv1, fmaf(h0.z, wv2, fmaf(h0.w, wv3, a0))));
        a1 = fmaf(h1.x, wv0, fmaf(h1.y, wv1, fmaf(h1.z, wv2, fmaf(h1.w, wv3, a1))));
        a2 = fmaf(h2.x, wv0, fmaf(h2.y, wv1, fmaf(h2.z, wv2, fmaf(h2.w, wv3, a2))));
        a3 = fmaf(h3.x, wv0, fmaf(h3.y, wv1, fmaf(h3.z, wv2, fmaf(h3.w, wv3, a3))));
    }
    if (!valid) return;

    // inverse permutation c -> d, with 1/2pi pre-scale on frequency/phase entries
    int d; float sc = 1.f;
    if (c < 2 * MID_DIM) {
        const int l = c / MID_DIM;
        const int rel = c - l * MID_DIM;
        if (rel < 8192) {
            const int o = rel >> 7, low = rel & 127;
            d = l * 12416 + (low & 1) * 4096 + (low >> 1) * 64 + o;
            sc = INV2PI;
        } else {
            const int r2 = rel - 8192;
            const int o = r2 / 65, j = r2 % 65;
            d = (j == 0) ? (l * 12416 + 12288 + o)
                         : (l * 12416 + 8192 + (j - 1) * 64 + o);
        }
    } else {
        const int rel = c - 2 * MID_DIM;
        if (rel < 128)       { d = 24832 + (rel & 1) * 64 + (rel >> 1); sc = INV2PI; }
        else if (rel == 128) { d = 24832 + 192; }
        else                 { d = 24832 + 128 + (rel - 129); }
    }
    const float bias = (kc == 0) ? b3[c] : 0.f;   // bias added exactly once per (b,c)
    atomicAdd(&mlpT[(size_t)0 * MLPT_STRIDE + d], (a0 + bias) * sc);
    atomicAdd(&mlpT[(size_t)1 * MLPT_STRIDE + d], (a1 + bias) * sc);
    atomicAdd(&mlpT[(size_t)2 * MLPT_STRIDE + d], (a2 + bias) * sc);
    atomicAdd(&mlpT[(size_t)3 * MLPT_STRIDE + d], (a3 + bias) * sc);
}

// ---------- fused ripple: layer0 -> layer1 -> out-layer + bypass ----------
// grid (SEQ/32, B), block 256 (4 waves x 8 t). lane = o.
__global__ void __launch_bounds__(256, 2) k_ripple(
        const float* __restrict__ mlpT, const float* __restrict__ lcw,
        const float* __restrict__ lcb, const float* __restrict__ bypw,
        const float* __restrict__ bypb, float* __restrict__ out) {
    const int tid = threadIdx.x;
    const int b = blockIdx.y;
    const int t0 = blockIdx.x * 32;
    const int lane = tid & 63, wid = tid >> 6, tb = wid * 8;

    __shared__ __align__(16) float s_w[12416];
    __shared__ __align__(16) float s_x[2304];    // x[i][t], stride 36
    __shared__ __align__(16) float s_wo[256];
    __shared__ float s_red[32];

    const float* mb = mlpT + (size_t)b * MLPT_STRIDE;

    {
        const float4* src = reinterpret_cast<const float4*>(mb);
        float4* dst = reinterpret_cast<float4*>(s_w);
        for (int e = tid; e < 3104; e += 256) dst[e] = src[e];
        if (tid < 64)
            reinterpret_cast<float4*>(s_wo)[tid] =
                reinterpret_cast<const float4*>(mb + 24832)[tid];
    }
    const float lw = lcw[lane], lb = lcb[lane];
    for (int e = tid; e < 2048; e += 256) {
        const int i = e >> 5, tt = e & 31;
        s_x[i * 36 + tt] = fmaf((float)(t0 + tt), lcw[i], lcb[i]);
    }
    __syncthreads();

    float acc[8];
    for (int layer = 0; layer < 2; ++layer) {
        const float bc = s_w[12288 + lane];
        #pragma unroll
        for (int j = 0; j < 8; ++j) acc[j] = bc;
        for (int i = 0; i < 64; ++i) {
            const float wsv = s_w[i * 64 + lane];
            const float wov = s_w[4096 + i * 64 + lane];
            const float bsv = s_w[8192 + i * 64 + lane];
            const float4 xa = *reinterpret_cast<const float4*>(&s_x[i * 36 + tb]);
            const float4 xb = *reinterpret_cast<const float4*>(&s_x[i * 36 + tb + 4]);
            const float xv[8] = {xa.x, xa.y, xa.z, xa.w, xb.x, xb.y, xb.z, xb.w};
            #pragma unroll
            for (int j = 0; j < 8; ++j) {
                const float r = fmaf(wsv, xv[j], wov);
                acc[j] = fmaf(hw_sin_rev(r), bsv, acc[j]);
            }
        }
        __syncthreads();
        if (layer == 0) {
            #pragma unroll
            for (int j = 0; j < 8; ++j)
                s_x[lane * 36 + tb + j] = gelu_exact(acc[j]);
            const float4* src = reinterpret_cast<const float4*>(mb + 12416);
            float4* dst = reinterpret_cast<float4*>(s_w);
            for (int e = tid; e < 3104; e += 256) dst[e] = src[e];
            __syncthreads();
        }
    }

    {
        const float wsO = s_wo[lane], woO = s_wo[64 + lane], bsO = s_wo[128 + lane];
        const float bcO = s_wo[192];
        const float bw0 = bypw[0] * INV2PI, bw1 = bypw[1] * INV2PI;
        const float bb0 = bypb[0], bb1 = bypb[1];
        #pragma unroll
        for (int j = 0; j < 8; ++j) {
            const int t = t0 + tb + j;
            const float v = gelu_exact(acc[j]);
            float s = hw_sin_rev(fmaf(wsO, v, woO)) * bsO;
            const float xb = fmaf((float)t, lw, lb);
            s = fmaf(hw_sin_rev(fmaf(bw0, xb, bw1)), bb1, s);
            #pragma unroll
            for (int m = 1; m < 64; m <<= 1) s += __shfl_xor(s, m, 64);
            if (lane == 0) s_red[tb + j] = s + bcO + bb0;
        }
    }
    __syncthreads();
    if (tid < 32) out[(size_t)b * SEQ + t0 + tid] = s_red[tid];
}

extern "C" void kernel_launch(void* const* d_in, const int* in_sizes, int n_in,
                              void* d_out, int out_size, void* d_ws, size_t ws_size,
                              hipStream_t stream) {
    const float* x    = (const float*)d_in[0];
    const float* w0   = (const float*)d_in[1];
    const float* b0   = (const float*)d_in[2];
    const float* w1   = (const float*)d_in[3];
    const float* b1   = (const float*)d_in[4];
    const float* g1   = (const float*)d_in[5];
    const float* bl1  = (const float*)d_in[6];
    const float* w2   = (const float*)d_in[7];
    const float* b2   = (const float*)d_in[8];
    const float* g2   = (const float*)d_in[9];
    const float* bl2  = (const float*)d_in[10];
    const float* w3   = (const float*)d_in[11];
    const float* b3   = (const float*)d_in[12];
    const float* lcw  = (const float*)d_in[13];
    const float* lcb  = (const float*)d_in[14];
    const float* bypw = (const float*)d_in[15];
    const float* bypb = (const float*)d_in[16];
    float* out = (float*)d_out;
    float* ws  = (float*)d_ws;

    float* p0   = ws + OFF_P0;
    float* p1   = ws + OFF_P1;
    float* p2   = ws + OFF_P2;
    float* mlpT = ws + OFF_MLPT;

    k_gemm0 <<<dim3(16, 8), 256, 0, stream>>>(x, w0, p0);
    k_gemm1 <<<dim3(16, 4), 256, 0, stream>>>(p0, b0, w1, p1);
    k_gemm2 <<<dim3(16, 4), 256, 0, stream>>>(p1, b1, g1, bl1, w2, p2);
    hipMemsetAsync(mlpT, 0, (size_t)B_ * MLPT_STRIDE * sizeof(float), stream);
    k_gemm3T<<<dim3(98, 8), 256, 0, stream>>>(p2, b2, g2, bl2, w3, b3, mlpT);
    k_ripple<<<dim3(SEQ / 32, B_), 256, 0, stream>>>(mlpT, lcw, lcb, bypw, bypb, out);
}

// Round 6
// 263.683 us; speedup vs baseline: 1.1761x; 1.1761x over previous
//
#include <hip/hip_runtime.h>
#include <math.h>

#define B_      4
#define IN_DIM  512
#define HID     1024
#define SEQ     4096
#define MID_DIM 12352          // 2*64*64 + 65*64
#define MLP_OUT 24897          // RL*MID_DIM + OUT_DIM
#define INV2PI  0.15915494309189535f

// transposed/pre-scaled weight layout, per b (stride MLPT_STRIDE):
//  layer l in {0,1} at l*12416: wsc[i][o] | wof[i][o] | bsv[i][o] | bc[o] | pad64
//  out layer at 24832: wsO/2pi (64) | woO/2pi (64) | bsO (64) | bcO | pad to 256
#define MLPT_STRIDE 25088

// ---- workspace layout (float offsets) ----
#define OFF_P0    0            // 8*4*1024 = 32768
#define OFF_P1    32768        // 4*4*1024 = 16384
#define OFF_P2    49152        // 4*4*1024 = 16384
#define OFF_H2    65536        // 4096
#define OFF_P3    69632        // 4*4*24897 = 398352
#define OFF_MLPT  467984       // 4*25088  = 100352

__device__ __forceinline__ float gelu_exact(float v) {
    return 0.5f * v * (1.0f + erff(v * 0.70710678118654752f));
}

__device__ __forceinline__ float hw_sin_rev(float r) {
    r = r - __builtin_rintf(r);
    return __builtin_amdgcn_sinf(r);
}

// ---------- x(4x512) @ w0 -> p0 (8 K-partials): grid (16,8), block 256 ----------
__global__ void k_gemm0(const float* __restrict__ x, const float* __restrict__ w0,
                        float* __restrict__ p0) {
    const int cch = blockIdx.x, kc = blockIdx.y;
    const int tid = threadIdx.x;
    __shared__ float xs[256];                 // [b][k64]
    {
        const int b = tid >> 6, k = tid & 63;
        xs[tid] = x[b * IN_DIM + kc * 64 + k];
    }
    __syncthreads();
    const int b = tid >> 6, cl = tid & 63;
    const int c = cch * 64 + cl;
    const float* wp = w0 + (size_t)(kc * 64) * HID + c;
    const float* xp = xs + b * 64;
    float acc = 0.f;
    #pragma unroll 16
    for (int k = 0; k < 64; ++k) acc = fmaf(xp[k], wp[(size_t)k * HID], acc);
    p0[(kc * 4 + b) * HID + c] = acc;
}

// ---------- h0=gelu(sum8 p0 + b0); h0 @ w1 -> p1 (4 K-partials): grid (16,4) ----------
__global__ void k_gemm1(const float* __restrict__ p0, const float* __restrict__ b0,
                        const float* __restrict__ w1, float* __restrict__ p1) {
    const int cch = blockIdx.x, kc = blockIdx.y;   // kc: 256-wide k slice
    const int tid = threadIdx.x;
    __shared__ float s_h[1024];               // [b][k256]
    for (int e = tid; e < 1024; e += 256) {
        const int b = e >> 8, kk = e & 255;
        const int kg = kc * 256 + kk;
        float v = b0[kg];
        #pragma unroll
        for (int j = 0; j < 8; ++j) v += p0[(j * 4 + b) * HID + kg];
        s_h[e] = gelu_exact(v);
    }
    __syncthreads();
    const int b = tid >> 6, cl = tid & 63;
    const int c = cch * 64 + cl;
    const float* wp = w1 + (size_t)(kc * 256) * HID + c;
    const float* hp = s_h + b * 256;
    float acc = 0.f;
    #pragma unroll 16
    for (int k = 0; k < 256; ++k) acc = fmaf(hp[k], wp[(size_t)k * HID], acc);
    p1[(kc * 4 + b) * HID + c] = acc;
}

// ---------- h1=gelu(LN(sum4 p1 + b1)) per block; h1 @ w2 -> p2 (4 K-partials): grid (16,4) ----------
__global__ void k_gemm2(const float* __restrict__ p1, const float* __restrict__ b1,
                        const float* __restrict__ g1, const float* __restrict__ bl1,
                        const float* __restrict__ w2, float* __restrict__ p2) {
    const int cch = blockIdx.x, kc = blockIdx.y;
    const int tid = threadIdx.x;
    __shared__ __align__(16) float vbuf[4096];   // [b][c]
    __shared__ float s_h[1024];                  // [b][k256]
    __shared__ float s_red[8];
    for (int e = tid; e < 4096; e += 256) {
        const int b = e >> 10, c = e & 1023;
        float v = b1[c];
        #pragma unroll
        for (int j = 0; j < 4; ++j) v += p1[(j * 4 + b) * HID + c];
        vbuf[e] = v;
    }
    __syncthreads();
    {
        const int b = tid >> 6, lane = tid & 63;
        float s1 = 0.f, s2 = 0.f;
        #pragma unroll
        for (int jj = 0; jj < 16; ++jj) {
            const float v = vbuf[b * 1024 + lane + 64 * jj];
            s1 += v; s2 += v * v;
        }
        #pragma unroll
        for (int m = 1; m < 64; m <<= 1) {
            s1 += __shfl_xor(s1, m, 64);
            s2 += __shfl_xor(s2, m, 64);
        }
        if (lane == 0) {
            const float mu = s1 * (1.0f / HID);
            s_red[b] = mu;
            s_red[4 + b] = rsqrtf(s2 * (1.0f / HID) - mu * mu + 1e-5f);
        }
    }
    __syncthreads();
    for (int e = tid; e < 1024; e += 256) {
        const int b = e >> 8, kk = e & 255;
        const int c = kc * 256 + kk;
        const float v = vbuf[b * 1024 + c];
        s_h[e] = gelu_exact((v - s_red[b]) * s_red[4 + b] * g1[c] + bl1[c]);
    }
    __syncthreads();
    const int b = tid >> 6, cl = tid & 63;
    const int c = cch * 64 + cl;
    const float* wp = w2 + (size_t)(kc * 256) * HID + c;
    const float* hp = s_h + b * 256;
    float acc = 0.f;
    #pragma unroll 16
    for (int k = 0; k < 256; ++k) acc = fmaf(hp[k], wp[(size_t)k * HID], acc);
    p2[(kc * 4 + b) * HID + c] = acc;
}

// ---------- h2 = gelu(LN(sum4 p2 + b2)): grid 4, block 1024 ----------
__global__ void k_lng2(const float* __restrict__ p2, const float* __restrict__ b2,
                       const float* __restrict__ g2, const float* __restrict__ bl2,
                       float* __restrict__ h2) {
    const int b = blockIdx.x, tid = threadIdx.x;
    float v = b2[tid];
    #pragma unroll
    for (int j = 0; j < 4; ++j) v += p2[(j * 4 + b) * HID + tid];
    float s1 = v, s2 = v * v;
    #pragma unroll
    for (int m = 1; m < 64; m <<= 1) {
        s1 += __shfl_xor(s1, m, 64);
        s2 += __shfl_xor(s2, m, 64);
    }
    __shared__ float r1[16], r2[16], s_mu, s_rs;
    const int lane = tid & 63, wid = tid >> 6;
    if (lane == 0) { r1[wid] = s1; r2[wid] = s2; }
    __syncthreads();
    if (tid == 0) {
        float a = 0.f, c = 0.f;
        #pragma unroll
        for (int j = 0; j < 16; ++j) { a += r1[j]; c += r2[j]; }
        const float mu = a * (1.0f / HID);
        s_mu = mu;
        s_rs = rsqrtf(c * (1.0f / HID) - mu * mu + 1e-5f);
    }
    __syncthreads();
    h2[b * HID + tid] = gelu_exact((v - s_mu) * s_rs * g2[tid] + bl2[tid]);
}

// ---------- h2(4x1024) @ w3 -> p3 (4 K-partials): grid (98,4), block 256 ----------
// thread = 1 column, 4 b-accumulators. 16-deep explicit prefetch double-buffer.
// h2 reads are wave-uniform -> scalar loads.
__global__ void k_gemm3(const float* __restrict__ h2, const float* __restrict__ w3,
                        float* __restrict__ p3) {
    const int colb = blockIdx.x;     // 0..97
    const int kc   = blockIdx.y;     // 0..3 (256 k's each)
    const int tid  = threadIdx.x;
    const int c_raw = colb * 256 + tid;
    const bool valid = c_raw < MLP_OUT;
    const int c = valid ? c_raw : (MLP_OUT - 1);
    const float* wp = w3 + (size_t)(kc * 256) * MLP_OUT + c;
    const float* hp = h2 + kc * 256;

    float a0 = 0.f, a1 = 0.f, a2 = 0.f, a3 = 0.f;
    float wb[16];
    #pragma unroll
    for (int j = 0; j < 16; ++j) wb[j] = wp[(size_t)j * MLP_OUT];

    for (int g = 0; g < 15; ++g) {
        const int k0 = g * 16;
        float wn[16];
        #pragma unroll
        for (int j = 0; j < 16; ++j) wn[j] = wp[(size_t)(k0 + 16 + j) * MLP_OUT];
        #pragma unroll
        for (int j = 0; j < 16; ++j) {
            const int k = k0 + j;
            a0 = fmaf(hp[k],        wb[j], a0);
            a1 = fmaf(hp[1024 + k], wb[j], a1);
            a2 = fmaf(hp[2048 + k], wb[j], a2);
            a3 = fmaf(hp[3072 + k], wb[j], a3);
        }
        #pragma unroll
        for (int j = 0; j < 16; ++j) wb[j] = wn[j];
    }
    #pragma unroll
    for (int j = 0; j < 16; ++j) {
        const int k = 240 + j;
        a0 = fmaf(hp[k],        wb[j], a0);
        a1 = fmaf(hp[1024 + k], wb[j], a1);
        a2 = fmaf(hp[2048 + k], wb[j], a2);
        a3 = fmaf(hp[3072 + k], wb[j], a3);
    }
    if (!valid) return;
    p3[(size_t)(kc * 4 + 0) * MLP_OUT + c] = a0;
    p3[(size_t)(kc * 4 + 1) * MLP_OUT + c] = a1;
    p3[(size_t)(kc * 4 + 2) * MLP_OUT + c] = a2;
    p3[(size_t)(kc * 4 + 3) * MLP_OUT + c] = a3;
}

// ---------- combine 4 partials + b3 -> permuted/pre-scaled mlpT: grid (98,4) ----------
// coalesced reads, scattered plain stores.
__global__ void k_comb3T(const float* __restrict__ p3, const float* __restrict__ b3,
                         float* __restrict__ mlpT) {
    const int b = blockIdx.y;
    const int c = blockIdx.x * 256 + threadIdx.x;
    if (c >= MLP_OUT) return;
    float v = b3[c];
    #pragma unroll
    for (int j = 0; j < 4; ++j) v += p3[(size_t)(j * 4 + b) * MLP_OUT + c];
    int d; float sc = 1.f;
    if (c < 2 * MID_DIM) {
        const int l = c / MID_DIM;
        const int rel = c - l * MID_DIM;
        if (rel < 8192) {
            const int o = rel >> 7, low = rel & 127;
            d = l * 12416 + (low & 1) * 4096 + (low >> 1) * 64 + o;
            sc = INV2PI;
        } else {
            const int r2 = rel - 8192;
            const int o = r2 / 65, j = r2 % 65;
            d = (j == 0) ? (l * 12416 + 12288 + o)
                         : (l * 12416 + 8192 + (j - 1) * 64 + o);
        }
    } else {
        const int rel = c - 2 * MID_DIM;
        if (rel < 128)       { d = 24832 + (rel & 1) * 64 + (rel >> 1); sc = INV2PI; }
        else if (rel == 128) { d = 24832 + 192; }
        else                 { d = 24832 + 128 + (rel - 129); }
    }
    mlpT[(size_t)b * MLPT_STRIDE + d] = v * sc;
}

// ---------- fused ripple: layer0 -> layer1 -> out-layer + bypass ----------
// grid (SEQ/32, B), block 256 (4 waves x 8 t). lane = o.
__global__ void __launch_bounds__(256, 2) k_ripple(
        const float* __restrict__ mlpT, const float* __restrict__ lcw,
        const float* __restrict__ lcb, const float* __restrict__ bypw,
        const float* __restrict__ bypb, float* __restrict__ out) {
    const int tid = threadIdx.x;
    const int b = blockIdx.y;
    const int t0 = blockIdx.x * 32;
    const int lane = tid & 63, wid = tid >> 6, tb = wid * 8;

    __shared__ __align__(16) float s_w[12416];
    __shared__ __align__(16) float s_x[2304];    // x[i][t], stride 36
    __shared__ __align__(16) float s_wo[256];
    __shared__ float s_red[32];

    const float* mb = mlpT + (size_t)b * MLPT_STRIDE;

    {
        const float4* src = reinterpret_cast<const float4*>(mb);
        float4* dst = reinterpret_cast<float4*>(s_w);
        for (int e = tid; e < 3104; e += 256) dst[e] = src[e];
        if (tid < 64)
            reinterpret_cast<float4*>(s_wo)[tid] =
                reinterpret_cast<const float4*>(mb + 24832)[tid];
    }
    const float lw = lcw[lane], lb = lcb[lane];
    for (int e = tid; e < 2048; e += 256) {
        const int i = e >> 5, tt = e & 31;
        s_x[i * 36 + tt] = fmaf((float)(t0 + tt), lcw[i], lcb[i]);
    }
    __syncthreads();

    float acc[8];
    for (int layer = 0; layer < 2; ++layer) {
        const float bc = s_w[12288 + lane];
        #pragma unroll
        for (int j = 0; j < 8; ++j) acc[j] = bc;
        for (int i = 0; i < 64; ++i) {
            const float wsv = s_w[i * 64 + lane];
            const float wov = s_w[4096 + i * 64 + lane];
            const float bsv = s_w[8192 + i * 64 + lane];
            const float4 xa = *reinterpret_cast<const float4*>(&s_x[i * 36 + tb]);
            const float4 xb = *reinterpret_cast<const float4*>(&s_x[i * 36 + tb + 4]);
            const float xv[8] = {xa.x, xa.y, xa.z, xa.w, xb.x, xb.y, xb.z, xb.w};
            #pragma unroll
            for (int j = 0; j < 8; ++j) {
                const float r = fmaf(wsv, xv[j], wov);
                acc[j] = fmaf(hw_sin_rev(r), bsv, acc[j]);
            }
        }
        __syncthreads();
        if (layer == 0) {
            #pragma unroll
            for (int j = 0; j < 8; ++j)
                s_x[lane * 36 + tb + j] = gelu_exact(acc[j]);
            const float4* src = reinterpret_cast<const float4*>(mb + 12416);
            float4* dst = reinterpret_cast<float4*>(s_w);
            for (int e = tid; e < 3104; e += 256) dst[e] = src[e];
            __syncthreads();
        }
    }

    {
        const float wsO = s_wo[lane], woO = s_wo[64 + lane], bsO = s_wo[128 + lane];
        const float bcO = s_wo[192];
        const float bw0 = bypw[0] * INV2PI, bw1 = bypw[1] * INV2PI;
        const float bb0 = bypb[0], bb1 = bypb[1];
        #pragma unroll
        for (int j = 0; j < 8; ++j) {
            const int t = t0 + tb + j;
            const float v = gelu_exact(acc[j]);
            float s = hw_sin_rev(fmaf(wsO, v, woO)) * bsO;
            const float xb = fmaf((float)t, lw, lb);
            s = fmaf(hw_sin_rev(fmaf(bw0, xb, bw1)), bb1, s);
            #pragma unroll
            for (int m = 1; m < 64; m <<= 1) s += __shfl_xor(s, m, 64);
            if (lane == 0) s_red[tb + j] = s + bcO + bb0;
        }
    }
    __syncthreads();
    if (tid < 32) out[(size_t)b * SEQ + t0 + tid] = s_red[tid];
}

extern "C" void kernel_launch(void* const* d_in, const int* in_sizes, int n_in,
                              void* d_out, int out_size, void* d_ws, size_t ws_size,
                              hipStream_t stream) {
    const float* x    = (const float*)d_in[0];
    const float* w0   = (const float*)d_in[1];
    const float* b0   = (const float*)d_in[2];
    const float* w1   = (const float*)d_in[3];
    const float* b1   = (const float*)d_in[4];
    const float* g1   = (const float*)d_in[5];
    const float* bl1  = (const float*)d_in[6];
    const float* w2   = (const float*)d_in[7];
    const float* b2   = (const float*)d_in[8];
    const float* g2   = (const float*)d_in[9];
    const float* bl2  = (const float*)d_in[10];
    const float* w3   = (const float*)d_in[11];
    const float* b3   = (const float*)d_in[12];
    const float* lcw  = (const float*)d_in[13];
    const float* lcb  = (const float*)d_in[14];
    const float* bypw = (const float*)d_in[15];
    const float* bypb = (const float*)d_in[16];
    float* out = (float*)d_out;
    float* ws  = (float*)d_ws;

    float* p0   = ws + OFF_P0;
    float* p1   = ws + OFF_P1;
    float* p2   = ws + OFF_P2;
    float* h2   = ws + OFF_H2;
    float* p3   = ws + OFF_P3;
    float* mlpT = ws + OFF_MLPT;

    k_gemm0 <<<dim3(16, 8), 256, 0, stream>>>(x, w0, p0);
    k_gemm1 <<<dim3(16, 4), 256, 0, stream>>>(p0, b0, w1, p1);
    k_gemm2 <<<dim3(16, 4), 256, 0, stream>>>(p1, b1, g1, bl1, w2, p2);
    k_lng2  <<<B_, 1024,    0, stream>>>(p2, b2, g2, bl2, h2);
    k_gemm3 <<<dim3(98, 4), 256, 0, stream>>>(h2, w3, p3);
    k_comb3T<<<dim3(98, 4), 256, 0, stream>>>(p3, b3, mlpT);
    k_ripple<<<dim3(SEQ / 32, B_), 256, 0, stream>>>(mlpT, lcw, lcb, bypw, bypb, out);
}